// Round 9
// baseline (12058.973 us; speedup 1.0000x reference)
//
#include <hip/hip_runtime.h>
#include <math.h>

#define VOCAB 256
#define DD    256     // hidden/embed dim
#define BB    32      // batch
#define LL    2048    // seq len
#define G4    1024    // 4*DD gate width
#define NB    16      // blocks per direction
#define TPB   512

typedef __attribute__((ext_vector_type(8))) short short8;
typedef __attribute__((ext_vector_type(4))) float floatx4;

__device__ __forceinline__ float sigf(float x) { return 1.0f / (1.0f + __expf(-x)); }

__device__ __forceinline__ unsigned short f2bf(float x) {
    unsigned u = __builtin_bit_cast(unsigned, x);
    u = u + 0x7fffu + ((u >> 16) & 1u);
    return (unsigned short)(u >> 16);
}
__device__ __forceinline__ float bf2f(unsigned short b) {
    unsigned u = ((unsigned)b) << 16;
    return __builtin_bit_cast(float, u);
}

// ---------------------------------------------------------------------------
// Kernel A: gates_table[dir][v][j] = sum_k embed[v][k] * w_dir[k][j] + b_dir[j]
// ---------------------------------------------------------------------------
__global__ __launch_bounds__(256) void k_table(
    const float* __restrict__ embed,
    const float* __restrict__ w_fwd, const float* __restrict__ b_fwd,
    const float* __restrict__ w_bwd, const float* __restrict__ b_bwd,
    float* __restrict__ tbl)
{
    const int dir = blockIdx.x >> 8;
    const int v   = blockIdx.x & 255;
    const float* __restrict__ w    = dir ? w_bwd : w_fwd;
    const float* __restrict__ bias = dir ? b_bwd : b_fwd;

    __shared__ __align__(16) float e[DD];
    const int tid = threadIdx.x;
    e[tid] = embed[v * DD + tid];
    __syncthreads();

    const float4* __restrict__ wx4 = (const float4*)w;  // [k][256] float4 groups
    float4 acc = ((const float4*)bias)[tid];
    #pragma unroll 2
    for (int k = 0; k < DD; k += 4) {
        float4 h4 = *(const float4*)&e[k];
        float4 w0 = wx4[(size_t)(k + 0) * 256 + tid];
        float4 w1 = wx4[(size_t)(k + 1) * 256 + tid];
        float4 w2 = wx4[(size_t)(k + 2) * 256 + tid];
        float4 w3 = wx4[(size_t)(k + 3) * 256 + tid];
        acc.x += h4.x * w0.x + h4.y * w1.x + h4.z * w2.x + h4.w * w3.x;
        acc.y += h4.x * w0.y + h4.y * w1.y + h4.z * w2.y + h4.w * w3.y;
        acc.z += h4.x * w0.z + h4.y * w1.z + h4.z * w2.z + h4.w * w3.z;
        acc.w += h4.x * w0.w + h4.y * w1.w + h4.z * w2.w + h4.w * w3.w;
    }
    ((float4*)tbl)[((size_t)dir * VOCAB + v) * 256 + tid] = acc;
}

// ---------------------------------------------------------------------------
// k_scan_b: batched bidirectional LSTM scan, TAGGED-DATAFLOW sync.
// 32 blocks = 2 dirs x NB col-slices; block (dir,j) owns hidden dims
// [16j,16j+16) for all 32 batches; weight slice lives in VGPRs as bf16
// hi/lo. Cross-block H exchange: one u64 per (b,dim):
//   (tag = s+1) << 32 | (bf16hi << 16 | bf16lo)
// stored with relaxed agent-scope atomics. Consumers poll their OWN data
// words until the tag matches the step — no counter, no tid0 funnel, one
// fabric round trip per step. Parity double-buffer; dataflow itself
// enforces that h(s) is not clobbered before every consumer has read it
// (a producer cannot finish step s+1 without reading all of h(s+1-1)).
// Backward rows in the reset region skip polling entirely (they need 0).
// ---------------------------------------------------------------------------
__global__ __launch_bounds__(TPB) void k_scan_b(
    const int*   __restrict__ ph,
    const int*   __restrict__ lens,
    const float* __restrict__ w_fwd,
    const float* __restrict__ w_bwd,
    const float* __restrict__ w_proj,
    const float* __restrict__ tbl,
    unsigned long long* __restrict__ Hpk_all,
    float* __restrict__ pp)
{
    const int dir  = blockIdx.x >> 4;
    const int j    = blockIdx.x & (NB - 1);
    const int tid  = threadIdx.x;
    const int lane = tid & 63;
    const int wv   = tid >> 6;        // wave 0..7
    const int mt   = wv >> 2;         // m-tile 0..1 (batches 16mt..16mt+15)
    const int gt   = wv & 3;          // gate 0..3 (i,g,f,o)

    const float* __restrict__ Wh = (dir ? w_bwd : w_fwd) + (size_t)DD * G4;
    const float* __restrict__ tb = tbl + (size_t)dir * VOCAB * G4;
    unsigned long long* __restrict__ Hd = Hpk_all + (size_t)dir * 2 * BB * DD;

    __shared__ unsigned short Ahi[BB * DD];   // 16KB, XOR-swizzled bf16 hi of H
    __shared__ unsigned short Alo[BB * DD];   // 16KB, lo
    __shared__ float gl[4][BB][17];           // padded gate exchange

    // persistent cell state: this thread owns cell (b, dd)
    const int b     = tid >> 4;
    const int dd    = tid & 15;
    const int dglob = j * 16 + dd;
    float c = 0.0f;
    const int   lenb = lens[b];
    const float wpd  = w_proj[dir * DD + dglob];

    // staging geometry: thread handles batch r, dims [o, o+16)
    const int r = tid >> 4;
    const int o = (tid & 15) * 16;

    // ---- preload this wave's weight fragments into registers (bf16 split) ----
    short8 bhi[8], blo[8];
    {
        const int ccol  = gt * DD + j * 16 + (lane & 15);  // global gate column
        const int krow0 = 8 * (lane >> 4);
        #pragma unroll
        for (int kk = 0; kk < 8; ++kk) {
            short8 th, tl;
            #pragma unroll
            for (int e = 0; e < 8; ++e) {
                float wval = Wh[(size_t)(kk * 32 + krow0 + e) * G4 + ccol];
                unsigned short hi = f2bf(wval);
                th[e] = (short)hi;
                tl[e] = (short)f2bf(wval - bf2f(hi));
            }
            bhi[kk] = th;
            blo[kk] = tl;
        }
    }

    // ---- initial x-gate gather (s = 0) ----
    float xg0, xg1, xg2, xg3;
    {
        const int t0 = dir ? (LL - 1) : 0;
        const int v  = ph[b * LL + t0];
        const float* __restrict__ trow = tb + (size_t)v * G4 + dglob;
        xg0 = trow[0]; xg1 = trow[DD]; xg2 = trow[2 * DD]; xg3 = trow[3 * DD];
    }

    for (int s = 0; s < LL; ++s) {
        const int t = dir ? (LL - 1 - s) : s;

        if (s) {
            // ---- stage H(prev): per-thread tag-poll of own 16 u64 words ----
            {
                const bool rz = (dir != 0) && (t < lenb - 1);   // reset: h==0
                unsigned pay[16];
                if (!rz) {
                    unsigned long long* __restrict__ src =
                        Hd + ((s & 1) ^ 1) * (BB * DD) + r * DD + o;
                    const unsigned tag = (unsigned)s;
                    unsigned pend = 0xFFFFu;
                    int guard = 0;
                    while (pend) {
                        #pragma unroll
                        for (int e = 0; e < 16; ++e) {
                            if (pend & (1u << e)) {
                                unsigned long long ue = __hip_atomic_load(
                                    src + e, __ATOMIC_RELAXED, __HIP_MEMORY_SCOPE_AGENT);
                                if ((unsigned)(ue >> 32) == tag) {
                                    pay[e] = (unsigned)ue;
                                    pend &= ~(1u << e);
                                }
                            }
                        }
                        if (pend) {
                            __builtin_amdgcn_s_sleep(1);
                            if (++guard > 50000000) break;   // safety valve vs hang
                        }
                    }
                } else {
                    #pragma unroll
                    for (int e = 0; e < 16; ++e) pay[e] = 0u;
                }
                // write swizzled bf16 hi/lo planes (8 dims per short8 chunk)
                #pragma unroll
                for (int hchunk = 0; hchunk < 2; ++hchunk) {
                    short8 sh, sl;
                    #pragma unroll
                    for (int e = 0; e < 8; ++e) {
                        const unsigned p = pay[8 * hchunk + e];
                        sh[e] = (short)(p >> 16);
                        sl[e] = (short)(p & 0xffffu);
                    }
                    const int k8   = (o >> 3) + hchunk;
                    const int byte = ((r * 32 + k8) << 4) ^ ((r & 7) << 4);
                    *(short8*)((char*)Ahi + byte) = sh;
                    *(short8*)((char*)Alo + byte) = sl;
                }
            }
            __syncthreads();

            // ---- MFMA: wave computes gate gt, m-tile mt, 16 cols ----
            {
                floatx4 acc = {0.f, 0.f, 0.f, 0.f};
                const int row = mt * 16 + (lane & 15);
                const int swz = (row & 7) << 4;
                const int k8b = lane >> 4;
                #pragma unroll
                for (int kk = 0; kk < 8; ++kk) {
                    const int byte = ((row * 32 + kk * 4 + k8b) << 4) ^ swz;
                    short8 ah = *(const short8*)((const char*)Ahi + byte);
                    short8 al = *(const short8*)((const char*)Alo + byte);
                    acc = __builtin_amdgcn_mfma_f32_16x16x32_bf16(ah, bhi[kk], acc, 0, 0, 0);
                    acc = __builtin_amdgcn_mfma_f32_16x16x32_bf16(al, bhi[kk], acc, 0, 0, 0);
                    acc = __builtin_amdgcn_mfma_f32_16x16x32_bf16(ah, blo[kk], acc, 0, 0, 0);
                }
                const int bl = mt * 16 + (lane >> 4) * 4;
                #pragma unroll
                for (int r2 = 0; r2 < 4; ++r2) gl[gt][bl + r2][lane & 15] = acc[r2];
            }
            __syncthreads();
        }

        // ---- cell update: thread (b,dd) ----
        float h;
        {
            float xi  = xg0;
            float xgg = xg1;
            float xf  = xg2;
            float xo  = xg3;
            if (s) {
                xi  += gl[0][b][dd];
                xgg += gl[1][b][dd];
                xf  += gl[2][b][dd];
                xo  += gl[3][b][dd];
            }
            if (dir && (t < lenb - 1)) c = 0.0f;   // hk.ResetCore: reset BEFORE step
            c = sigf(xf + 1.0f) * c + sigf(xi) * tanhf(xgg);
            h = sigf(xo) * tanhf(c);
            const unsigned short hhi = f2bf(h);
            const unsigned short hlo = f2bf(h - bf2f(hhi));
            const unsigned long long upk =
                ((unsigned long long)(unsigned)(s + 1) << 32) |
                (unsigned long long)(((unsigned)hhi << 16) | (unsigned)hlo);
            __hip_atomic_store(Hd + (s & 1) * (BB * DD) + b * DD + dglob, upk,
                               __ATOMIC_RELAXED, __HIP_MEMORY_SCOPE_AGENT);
        }

        // ---- off-critical-path: projection partial + next-step gather ----
        {
            float pr = h * wpd;
            pr += __shfl_xor(pr, 1, 16);
            pr += __shfl_xor(pr, 2, 16);
            pr += __shfl_xor(pr, 4, 16);
            pr += __shfl_xor(pr, 8, 16);
            if (dd == 0) pp[((size_t)(dir * NB + j) * BB + b) * LL + t] = pr;
        }
        if (s + 1 < LL) {
            const int tn = dir ? (LL - 2 - s) : (s + 1);
            const int v  = ph[b * LL + tn];
            const float* __restrict__ trow = tb + (size_t)v * G4 + dglob;
            xg0 = trow[0]; xg1 = trow[DD]; xg2 = trow[2 * DD]; xg3 = trow[3 * DD];
        }
    }
}

// ---------------------------------------------------------------------------
// k_comb: out[b,t] = relu( sum over 32 (dir,j) partials + b_proj )
// ---------------------------------------------------------------------------
__global__ __launch_bounds__(256) void k_comb(
    const float* __restrict__ pp,
    const float* __restrict__ b_proj,
    float* __restrict__ out)
{
    const int i = blockIdx.x * 256 + threadIdx.x;   // i = b*LL + t
    float sv = b_proj[0];
    #pragma unroll
    for (int q = 0; q < 2 * NB; ++q) sv += pp[(size_t)q * (BB * LL) + i];
    out[i] = sv > 0.0f ? sv : 0.0f;
}

extern "C" void kernel_launch(void* const* d_in, const int* in_sizes, int n_in,
                              void* d_out, int out_size, void* d_ws, size_t ws_size,
                              hipStream_t stream)
{
    const int*   phon = (const int*)d_in[0];
    const int*   lens = (const int*)d_in[1];
    const float* emb  = (const float*)d_in[2];
    const float* wf   = (const float*)d_in[3];
    const float* bf   = (const float*)d_in[4];
    const float* wb   = (const float*)d_in[5];
    const float* bbi  = (const float*)d_in[6];
    const float* wp   = (const float*)d_in[7];
    const float* bp   = (const float*)d_in[8];
    float* out = (float*)d_out;

    float* ws  = (float*)d_ws;
    float* tbl = ws;                                  // 2*256*1024   f (2 MB)
    float* pp  = tbl + 2 * VOCAB * G4;                // 2*16*32*2048 f (8 MB)
    unsigned long long* Hpk =
        (unsigned long long*)(pp + (size_t)2 * NB * BB * LL);  // 2*2*32*256 u64 (256 KB)
    // NOTE: ws poisoned to 0xAA each launch -> stale tags are 0xAAAAAAAA,
    // never equal to a live tag in [1, 2048]; no zero-init kernel needed.

    k_table <<<2 * VOCAB, 256, 0, stream>>>(emb, wf, bf, wb, bbi, tbl);
    k_scan_b<<<2 * NB, TPB, 0, stream>>>(phon, lens, wf, wb, wp, tbl, Hpk, pp);
    k_comb  <<<(BB * LL) / 256, 256, 0, stream>>>(pp, bp, out);
}